// Round 3
// baseline (453.498 us; speedup 1.0000x reference)
//
#include <hip/hip_runtime.h>
#include <stdint.h>

// ---------------- problem constants ----------------
#define B_   2
#define S_   1024
#define D_   512
#define G_   8
#define H_   8
#define QKD_ 64
#define VD_  64
#define T_   (B_ * S_)        // 2048 rows
#define QC_  (G_ * H_ * QKD_) // 4096 q/z columns
#define KVC_ (G_ * (QKD_ + VD_)) // 1024 kv columns

typedef __attribute__((ext_vector_type(8))) short short8;
typedef __attribute__((ext_vector_type(4))) float f32x4;

__device__ __forceinline__ unsigned short f2bf(float f) {
    unsigned u = __builtin_bit_cast(unsigned, f);
    u += 0x7FFF + ((u >> 16) & 1);   // RNE
    return (unsigned short)(u >> 16);
}

// ---------------- conversions ----------------
__global__ __launch_bounds__(256) void f32_to_bf16_vec(
    const float* __restrict__ in, unsigned short* __restrict__ out, int n4)
{
    int i = blockIdx.x * 256 + threadIdx.x;
    if (i >= n4) return;
    float4 v = ((const float4*)in)[i];
    ushort4 o;
    o.x = f2bf(v.x); o.y = f2bf(v.y); o.z = f2bf(v.z); o.w = f2bf(v.w);
    ((ushort4*)out)[i] = o;
}

// in [K][N] f32  ->  out [N][K] bf16   (all dims multiples of 32)
__global__ __launch_bounds__(256) void transpose_f32_bf16(
    const float* __restrict__ in, unsigned short* __restrict__ out, int K, int N)
{
    __shared__ float tile[32][33];
    int n0 = blockIdx.x * 32, k0 = blockIdx.y * 32;
    int tx = threadIdx.x & 31, ty = threadIdx.x >> 5;
    #pragma unroll
    for (int i = 0; i < 4; i++)
        tile[ty + i * 8][tx] = in[(size_t)(k0 + ty + i * 8) * N + n0 + tx];
    __syncthreads();
    #pragma unroll
    for (int i = 0; i < 4; i++)
        out[(size_t)(n0 + ty + i * 8) * K + k0 + tx] = f2bf(tile[tx][ty + i * 8]);
}

// split KV [T][1024] into K [B*G][S][64] and Vt [B*G][64][S]
__global__ __launch_bounds__(256) void scatter_kv(
    const unsigned short* __restrict__ KVb,
    unsigned short* __restrict__ Kb, unsigned short* __restrict__ Vtb)
{
    int idx = blockIdx.x * 256 + threadIdx.x;
    if (idx >= T_ * KVC_) return;
    int t = idx >> 10, c = idx & 1023;
    int b = t >> 10, s = t & 1023;
    unsigned short v = KVb[idx];
    if (c < G_ * QKD_) {
        int g = c >> 6, d = c & 63;
        Kb[((size_t)(b * G_ + g) * S_ + s) * 64 + d] = v;
    } else {
        int c2 = c - G_ * QKD_;
        int g = c2 >> 6, d = c2 & 63;
        Vtb[((size_t)(b * G_ + g) * 64 + d) * S_ + s] = v;
    }
}

// ---------------- GEMM: C[M,N] = A[M,K] * Bt[N,K]^T + bias ----------------
// OUT_MODE 0: bf16 store. OUT_MODE 1: f32 store with leaky_relu(0.01).
template <int OUT_MODE>
__global__ __launch_bounds__(256) void gemm_bt(
    const unsigned short* __restrict__ A,
    const unsigned short* __restrict__ Bt,
    const float* __restrict__ bias,
    void* __restrict__ Cout,
    int M, int N, int K)
{
    constexpr int BM = 128, BN = 128, BK = 32, LDT = 40; // 80B padded rows
    __shared__ __attribute__((aligned(16))) unsigned short As[BM * LDT];
    __shared__ __attribute__((aligned(16))) unsigned short Bs[BN * LDT];
    const int tid = threadIdx.x;
    const int m0 = blockIdx.y * BM, n0 = blockIdx.x * BN;
    const int lane = tid & 63, w = tid >> 6;
    const int wm = w >> 1, wn = w & 1;
    const int cl = lane & 15, gr = lane >> 4;

    f32x4 acc[4][4];
    #pragma unroll
    for (int i = 0; i < 4; i++)
        #pragma unroll
        for (int j = 0; j < 4; j++) acc[i][j] = {0.f, 0.f, 0.f, 0.f};

    // two 16B chunks per matrix per thread per K-tile
    const int o0 = tid * 16;              // byte offset in 8KB tile
    const int row0 = o0 >> 6, ce0 = (o0 & 63) >> 1;
    const int o1 = o0 + 4096;
    const int row1 = o1 >> 6, ce1 = (o1 & 63) >> 1;

    const int nkt = K / BK;
    for (int kt = 0; kt < nkt; kt++) {
        const int k0 = kt * BK;
        int4 a0 = *(const int4*)(A + (size_t)(m0 + row0) * K + k0 + ce0);
        int4 a1 = *(const int4*)(A + (size_t)(m0 + row1) * K + k0 + ce1);
        int4 b0 = *(const int4*)(Bt + (size_t)(n0 + row0) * K + k0 + ce0);
        int4 b1 = *(const int4*)(Bt + (size_t)(n0 + row1) * K + k0 + ce1);
        __syncthreads();
        *(int4*)&As[row0 * LDT + ce0] = a0;
        *(int4*)&As[row1 * LDT + ce1] = a1;
        *(int4*)&Bs[row0 * LDT + ce0] = b0;
        *(int4*)&Bs[row1 * LDT + ce1] = b1;
        __syncthreads();
        short8 af[4], bfr[4];
        #pragma unroll
        for (int mr = 0; mr < 4; mr++)
            af[mr] = *(const short8*)&As[(wm * 64 + mr * 16 + cl) * LDT + gr * 8];
        #pragma unroll
        for (int nr = 0; nr < 4; nr++)
            bfr[nr] = *(const short8*)&Bs[(wn * 64 + nr * 16 + cl) * LDT + gr * 8];
        #pragma unroll
        for (int mr = 0; mr < 4; mr++)
            #pragma unroll
            for (int nr = 0; nr < 4; nr++)
                acc[mr][nr] = __builtin_amdgcn_mfma_f32_16x16x32_bf16(
                    af[mr], bfr[nr], acc[mr][nr], 0, 0, 0);
    }

    #pragma unroll
    for (int mr = 0; mr < 4; mr++) {
        #pragma unroll
        for (int nr = 0; nr < 4; nr++) {
            const int col = n0 + wn * 64 + nr * 16 + cl;
            const float bv = bias[col];
            #pragma unroll
            for (int j = 0; j < 4; j++) {
                const int row = m0 + wm * 64 + mr * 16 + gr * 4 + j;
                float v = acc[mr][nr][j] + bv;
                if (OUT_MODE == 0) {
                    ((unsigned short*)Cout)[(size_t)row * N + col] = f2bf(v);
                } else {
                    v = v > 0.f ? v : 0.01f * v;
                    ((float*)Cout)[(size_t)row * N + col] = v;
                }
            }
        }
    }
}

// ---------------- flash attention ----------------
// grid: 128 heads * 16 q-tiles; block: 4 waves, each wave owns 16 q-rows.
__global__ __launch_bounds__(256) void attn_kernel(
    const unsigned short* __restrict__ Qb,   // [T][4096]
    const unsigned short* __restrict__ Kb,   // [B*G][S][64]
    const unsigned short* __restrict__ Vtb,  // [B*G][64][S]
    unsigned short* __restrict__ Zb)         // [T][4096]
{
    __shared__ __attribute__((aligned(16))) unsigned short Pl[4][16][40];
    const int tid = threadIdx.x;
    const int w = tid >> 6, lane = tid & 63;
    const int cl = lane & 15, gr = lane >> 4;
    const int bid = blockIdx.x;
    const int qt = bid & 15, head = bid >> 4;
    const int b = head >> 6, gh = head & 63;
    const int g = gh >> 3;
    const int qrow0 = qt * 64 + w * 16;

    const unsigned short* Qp =
        Qb + (size_t)(b * S_ + qrow0 + cl) * QC_ + gh * 64 + gr * 8;
    const short8 q0 = *(const short8*)(Qp);
    const short8 q1 = *(const short8*)(Qp + 32);

    const unsigned short* Kp = Kb + (size_t)(b * G_ + g) * (S_ * 64);
    const unsigned short* Vp = Vtb + (size_t)(b * G_ + g) * (64 * S_);

    float m[4], l[4];
    #pragma unroll
    for (int j = 0; j < 4; j++) { m[j] = -1e30f; l[j] = 0.f; }
    f32x4 acc[4];
    #pragma unroll
    for (int d = 0; d < 4; d++) acc[d] = {0.f, 0.f, 0.f, 0.f};

    for (int kt = 0; kt < S_ / 32; kt++) {
        const int key0 = kt * 32;
        f32x4 s[2];
        #pragma unroll
        for (int ct = 0; ct < 2; ct++) {
            const unsigned short* kp = Kp + (size_t)(key0 + ct * 16 + cl) * 64 + gr * 8;
            short8 kf0 = *(const short8*)(kp);
            short8 kf1 = *(const short8*)(kp + 32);
            f32x4 z = {0.f, 0.f, 0.f, 0.f};
            z = __builtin_amdgcn_mfma_f32_16x16x32_bf16(q0, kf0, z, 0, 0, 0);
            z = __builtin_amdgcn_mfma_f32_16x16x32_bf16(q1, kf1, z, 0, 0, 0);
            s[ct] = z * 0.125f;   // 1/sqrt(64)
        }
        // online softmax over the 32-key tile (row lives across 16 lanes)
        float tmax[4];
        #pragma unroll
        for (int j = 0; j < 4; j++) tmax[j] = fmaxf(s[0][j], s[1][j]);
        #pragma unroll
        for (int off = 1; off < 16; off <<= 1)
            #pragma unroll
            for (int j = 0; j < 4; j++)
                tmax[j] = fmaxf(tmax[j], __shfl_xor(tmax[j], off));
        float corr[4], rs[4], p0[4], p1[4];
        #pragma unroll
        for (int j = 0; j < 4; j++) {
            float mn = fmaxf(m[j], tmax[j]);
            corr[j] = __expf(m[j] - mn);
            m[j] = mn;
            p0[j] = __expf(s[0][j] - mn);
            p1[j] = __expf(s[1][j] - mn);
            rs[j] = p0[j] + p1[j];
        }
        #pragma unroll
        for (int off = 1; off < 16; off <<= 1)
            #pragma unroll
            for (int j = 0; j < 4; j++)
                rs[j] += __shfl_xor(rs[j], off);
        #pragma unroll
        for (int j = 0; j < 4; j++) l[j] = l[j] * corr[j] + rs[j];
        #pragma unroll
        for (int d = 0; d < 4; d++)
            #pragma unroll
            for (int j = 0; j < 4; j++)
                acc[d][j] *= corr[j];
        // P (C-layout) -> LDS -> A-frag layout
        __syncthreads();
        #pragma unroll
        for (int j = 0; j < 4; j++) {
            Pl[w][gr * 4 + j][cl]      = f2bf(p0[j]);
            Pl[w][gr * 4 + j][16 + cl] = f2bf(p1[j]);
        }
        __syncthreads();
        const short8 pa = *(const short8*)&Pl[w][cl][gr * 8];
        #pragma unroll
        for (int d = 0; d < 4; d++) {
            const unsigned short* vp = Vp + (size_t)(d * 16 + cl) * S_ + key0 + gr * 8;
            short8 vf = *(const short8*)(vp);
            acc[d] = __builtin_amdgcn_mfma_f32_16x16x32_bf16(pa, vf, acc[d], 0, 0, 0);
        }
    }

    #pragma unroll
    for (int d = 0; d < 4; d++)
        #pragma unroll
        for (int j = 0; j < 4; j++) {
            const int row = qrow0 + gr * 4 + j;
            Zb[(size_t)(b * S_ + row) * QC_ + gh * 64 + d * 16 + cl] =
                f2bf(acc[d][j] / l[j]);
        }
}

// ---------------- launch ----------------
extern "C" void kernel_launch(void* const* d_in, const int* in_sizes, int n_in,
                              void* d_out, int out_size, void* d_ws, size_t ws_size,
                              hipStream_t stream)
{
    const float* x     = (const float*)d_in[0];
    const float* Wq_w  = (const float*)d_in[1];
    const float* Wq_b  = (const float*)d_in[2];
    const float* Wkv_w = (const float*)d_in[3];
    const float* Wkv_b = (const float*)d_in[4];
    const float* Wz_w  = (const float*)d_in[5];
    const float* Wz_b  = (const float*)d_in[6];
    float* out = (float*)d_out;

    unsigned short* ws   = (unsigned short*)d_ws;
    unsigned short* xb   = ws;                               // [2048][512]
    unsigned short* WqT  = xb   + (size_t)T_ * D_;           // [4096][512]
    unsigned short* WkvT = WqT  + (size_t)QC_ * D_;          // [1024][512]
    unsigned short* WzT  = WkvT + (size_t)KVC_ * D_;         // [512][4096]
    unsigned short* Qb   = WzT  + (size_t)D_ * QC_;          // [2048][4096]
    unsigned short* KVb  = Qb   + (size_t)T_ * QC_;          // [2048][1024]
    unsigned short* Kb   = KVb  + (size_t)T_ * KVC_;         // [16][1024][64]
    unsigned short* Vtb  = Kb   + (size_t)B_ * G_ * S_ * 64; // [16][64][1024]
    unsigned short* Zb   = Vtb  + (size_t)B_ * G_ * 64 * S_; // [2048][4096]

    f32_to_bf16_vec<<<(T_ * D_ / 4 + 255) / 256, 256, 0, stream>>>(x, xb, T_ * D_ / 4);
    transpose_f32_bf16<<<dim3(QC_ / 32, D_ / 32), 256, 0, stream>>>(Wq_w, WqT, D_, QC_);
    transpose_f32_bf16<<<dim3(KVC_ / 32, D_ / 32), 256, 0, stream>>>(Wkv_w, WkvT, D_, KVC_);
    transpose_f32_bf16<<<dim3(D_ / 32, QC_ / 32), 256, 0, stream>>>(Wz_w, WzT, QC_, D_);

    gemm_bt<0><<<dim3(QC_ / 128, T_ / 128), 256, 0, stream>>>(xb, WqT, Wq_b, Qb, T_, QC_, D_);
    gemm_bt<0><<<dim3(KVC_ / 128, T_ / 128), 256, 0, stream>>>(xb, WkvT, Wkv_b, KVb, T_, KVC_, D_);
    scatter_kv<<<(T_ * KVC_ + 255) / 256, 256, 0, stream>>>(KVb, Kb, Vtb);
    attn_kernel<<<B_ * G_ * H_ * (S_ / 64), 256, 0, stream>>>(Qb, Kb, Vtb, Zb);
    gemm_bt<1><<<dim3(D_ / 128, T_ / 128), 256, 0, stream>>>(Zb, WzT, Wz_b, out, T_, D_, QC_);
}